// Round 11
// baseline (213.694 us; speedup 1.0000x reference)
//
#include <hip/hip_runtime.h>
#include <hip/hip_bf16.h>
#include <cstdint>
#include <cstddef>

// Problem constants (B,N,M,C2,C1) = (4, 8192, 2048, 256, 128)
static constexpr int BB   = 4;
static constexpr int NN   = 8192;
static constexpr int MM   = 2048;
static constexpr int C1   = 128;
static constexpr int C2   = 256;
static constexpr int CH0  = C2 + C1;   // 384  (K of GEMM0)
static constexpr int O0   = 256;       // out channels layer 0
static constexpr int O1   = 128;       // out channels layer 1
static constexpr int NCOL = BB * NN;   // 32768 columns
static constexpr float BN_EPS = 1e-5f;

using u16 = unsigned short;
typedef __attribute__((ext_vector_type(8))) short short8;
typedef __attribute__((ext_vector_type(4))) float f32x4;

static __device__ __forceinline__ float bf2f(u16 u) {
    union { unsigned int i; float f; } v; v.i = ((unsigned int)u) << 16; return v.f;
}
static __device__ __forceinline__ u16 f2bf(float f) {
    union { float f; unsigned int i; } v; v.f = f;
    unsigned int r = (v.i + 0x7fffu + ((v.i >> 16) & 1u)) >> 16;
    return (u16)r;
}

// ---------------------------------------------------------------------------
// K1 (merged prep): blocks 0..2047 transpose points2 (256x2048 -> 2048x256),
// blocks 2048..6143 transpose points1 (128x8192 -> 8192x128),
// blocks 6144..6655 cast W0,W1 f32->bf16.
__global__ __launch_bounds__(256) void prep_kernel(const float* __restrict__ points2,
                                                   u16* __restrict__ p2T,
                                                   const float* __restrict__ points1,
                                                   u16* __restrict__ p1T,
                                                   const float* __restrict__ W0f,
                                                   u16* __restrict__ W0b,
                                                   const float* __restrict__ W1f,
                                                   u16* __restrict__ W1b) {
    __shared__ float tile[32][33];
    int id = blockIdx.x;
    int t  = threadIdx.x;
    if (id < 6144) {
        const float* in; u16* out; int R, C, b, c0, r0;
        if (id < 2048) {
            in = points2; out = p2T; R = C2; C = MM;
            b = id >> 9; int rem = id & 511;
            c0 = (rem & 63) * 32; r0 = (rem >> 6) * 32;
        } else {
            int id2 = id - 2048;
            in = points1; out = p1T; R = C1; C = NN;
            b = id2 >> 10; int rem = id2 & 1023;
            c0 = (rem & 255) * 32; r0 = (rem >> 8) * 32;
        }
        int tx = t & 31, ty = t >> 5;        // (32,8)
        const float* pin = in + (size_t)b * R * C;
        u16* pout = out + (size_t)b * R * C;
#pragma unroll
        for (int j = 0; j < 4; ++j) {
            int r = ty + j * 8;
            tile[r][tx] = pin[(size_t)(r0 + r) * C + (c0 + tx)];
        }
        __syncthreads();
#pragma unroll
        for (int j = 0; j < 4; ++j) {
            int c = ty + j * 8;
            pout[(size_t)(c0 + c) * R + (r0 + tx)] = f2bf(tile[tx][c]);
        }
    } else {
        int i = (id - 6144) * 256 + t;
        if (i < O0 * CH0) W0b[i] = f2bf(W0f[i]);
        else {
            int i2 = i - O0 * CH0;
            if (i2 < O1 * O0) W1b[i2] = f2bf(W1f[i2]);
        }
    }
}

// ---------------------------------------------------------------------------
// K2: 3-NN + combined (distance * normal) interpolation weights. f32 inputs.
// TWO queries per thread (halves LDS-pipe traffic, the measured bottleneck),
// 8 lanes per query scanning stride-8; branchless sorted top-3 insert;
// 3-step shfl_xor merge with lexicographic (d, idx) tie-break (= top_k).
// Distance replicates (qq + pp) - 2*qp with fp contract off.
__global__ __launch_bounds__(256) void three_nn_kernel(const float* __restrict__ xyz1,
                                                       const float* __restrict__ xyz2,
                                                       const float* __restrict__ norm1,
                                                       const float* __restrict__ norm2,
                                                       int* __restrict__ idxOut,
                                                       float* __restrict__ wOut) {
#pragma clang fp contract(off)
    constexpr int CH = 1024;             // points per LDS chunk
    __shared__ float4 pts[CH];
    int b    = blockIdx.x >> 7;          // 128 blocks of 64 queries per batch
    int nblk = blockIdx.x & 127;
    int t    = threadIdx.x;
    int j    = t & 7;                    // lane within the 8-thread query group

    int n0 = nblk * 64 + (t >> 3) * 2;
    int n1 = n0 + 1;
    const float* x1 = xyz1 + (size_t)b * 3 * NN;
    float qxa = x1[n0], qya = x1[NN + n0], qza = x1[2 * NN + n0];
    float qxb = x1[n1], qyb = x1[NN + n1], qzb = x1[2 * NN + n1];
    float qqa = (qxa * qxa + qya * qya) + qza * qza;
    float qqb = (qxb * qxb + qyb * qyb) + qzb * qzb;

    const float* x2 = xyz2 + (size_t)b * 3 * MM;

    float da0 = 3.4e38f, da1 = 3.4e38f, da2 = 3.4e38f;
    int   ia0 = 0, ia1 = 0, ia2 = 0;
    float db0 = 3.4e38f, db1 = 3.4e38f, db2 = 3.4e38f;
    int   ib0 = 0, ib1 = 0, ib2 = 0;

    auto ins = [](float d, int m, float& e0, float& e1, float& e2,
                  int& f0, int& f1, int& f2) {
        bool m0 = d < e0, m1 = d < e1, m2 = d < e2;
        e2 = m1 ? e1 : (m2 ? d : e2);
        f2 = m1 ? f1 : (m2 ? m : f2);
        e1 = m0 ? e0 : (m1 ? d : e1);
        f1 = m0 ? f0 : (m1 ? m : f1);
        e0 = m0 ? d : e0;
        f0 = m0 ? m : f0;
    };

    for (int chunk = 0; chunk < MM / CH; ++chunk) {
        __syncthreads();                 // prior scan done before overwrite
        for (int i = t; i < CH; i += 256) {
            int m = chunk * CH + i;
            float px = x2[m];
            float py = x2[MM + m];
            float pz = x2[2 * MM + m];
            float pp = (px * px + py * py) + pz * pz;
            pts[i] = make_float4(px, py, pz, pp);
        }
        __syncthreads();

#pragma unroll 4
        for (int s = 0; s < CH / 8; ++s) {
            int ml = s * 8 + j;          // ascending per thread -> stable ties
            float4 P = pts[ml];
            int m = chunk * CH + ml;
            float qpa = (qxa * P.x + qya * P.y) + qza * P.z;
            float da  = (qqa + P.w) - 2.0f * qpa;
            ins(da, m, da0, da1, da2, ia0, ia1, ia2);
            float qpb = (qxb * P.x + qyb * P.y) + qzb * P.z;
            float db  = (qqb + P.w) - 2.0f * qpb;
            ins(db, m, db0, db1, db2, ib0, ib1, ib2);
        }
    }

    // merge sorted triples across the 8 lanes of each group (lex tie-break)
    auto merge = [&](float& e0, float& e1, float& e2, int& f0, int& f1, int& f2) {
#pragma unroll
        for (int k = 1; k <= 4; k <<= 1) {
            float g0 = __shfl_xor(e0, k, 64), g1 = __shfl_xor(e1, k, 64), g2 = __shfl_xor(e2, k, 64);
            int   h0 = __shfl_xor(f0, k, 64), h1 = __shfl_xor(f1, k, 64), h2 = __shfl_xor(f2, k, 64);
            float ed[3] = {g0, g1, g2}; int ef[3] = {h0, h1, h2};
#pragma unroll
            for (int e = 0; e < 3; ++e) {
                float dd = ed[e]; int ff = ef[e];
                bool b2 = (dd < e2) || (dd == e2 && ff < f2);
                if (b2) {
                    bool b1 = (dd < e1) || (dd == e1 && ff < f1);
                    if (b1) {
                        e2 = e1; f2 = f1;
                        bool b0 = (dd < e0) || (dd == e0 && ff < f0);
                        if (b0) { e1 = e0; f1 = f0; e0 = dd; f0 = ff; }
                        else    { e1 = dd; f1 = ff; }
                    } else { e2 = dd; f2 = ff; }
                }
            }
        }
    };
    merge(da0, da1, da2, ia0, ia1, ia2);
    merge(db0, db1, db2, ib0, ib1, ib2);

    if (j == 0) {
        const float* nm1 = norm1 + (size_t)b * 3 * NN;
        const float* nm2 = norm2 + (size_t)b * 3 * MM;
        auto emit = [&](int n, float e0, float e1, float e2, int f0, int f1, int f2) {
            float s0 = sqrtf(fmaxf(e0, 1e-20f));
            float s1 = sqrtf(fmaxf(e1, 1e-20f));
            float s2 = sqrtf(fmaxf(e2, 1e-20f));
            float r0 = 1.0f / fmaxf(s0, 1e-10f);
            float r1 = 1.0f / fmaxf(s1, 1e-10f);
            float r2 = 1.0f / fmaxf(s2, 1e-10f);
            float rs = (r0 + r1) + r2;
            float w0 = r0 / rs, w1 = r1 / rs, w2 = r2 / rs;
            float ax = nm1[n], ay = nm1[NN + n], az = nm1[2 * NN + n];
            float nd[3]; int ii[3] = {f0, f1, f2};
#pragma unroll
            for (int k = 0; k < 3; ++k) {
                int ik = ii[k];
                float dx = ax - nm2[ik];
                float dy = ay - nm2[MM + ik];
                float dz = az - nm2[2 * MM + ik];
                nd[k] = sqrtf((dx * dx + dy * dy) + dz * dz);
            }
            float m0 = 1.0f / fmaxf(nd[0], 1e-10f);
            float m1 = 1.0f / fmaxf(nd[1], 1e-10f);
            float m2 = 1.0f / fmaxf(nd[2], 1e-10f);
            float ms = (m0 + m1) + m2;
            int col = b * NN + n;
            idxOut[col * 3 + 0] = f0;
            idxOut[col * 3 + 1] = f1;
            idxOut[col * 3 + 2] = f2;
            wOut[col * 3 + 0] = w0 * (m0 / ms);
            wOut[col * 3 + 1] = w1 * (m1 / ms);
            wOut[col * 3 + 2] = w2 * (m2 / ms);
        };
        emit(n0, da0, da1, da2, ia0, ia1, ia2);
        emit(n1, db0, db1, db2, ib0, ib1, ib2);
    }
}

// ---------------------------------------------------------------------------
// K4/K6: GEMM  C^T[col][m] = sum_k A[m][k] * Bsrc[col][k] + bias[m]
// 128 rows x COLT cols, BK=64, 256 threads, 16x16x32 bf16 MFMA.
// A staging: async global_load_lds (16B/lane), XOR-swizzled, double-buffered.
// B staging by MODE:
//   0: DMA from Bt (K-contiguous B^T).
//   1: VGPR path from Bt applying relu(f*sc+sh); sc/sh folded in PROLOGUE
//      from 16-record reduced stats redB + gB/beB (fused BN+ReLU).
//   2: k<256: VGPR gather-interpolate from p2T (Bt) using idx/w (fused
//      three_interpolate; kills the xT materialization); k>=256: DMA p1T.
// BN stats out: shuffle-reduce -> LDS atomics -> one partial record/block.
template <int KDIM, int LDC, int COLT, int MODE>
__global__ __launch_bounds__(256) void gemm_bt_kernel(const u16* __restrict__ A,
                                                      const u16* __restrict__ Bt,
                                                      const u16* __restrict__ p1T,
                                                      const int* __restrict__ idx,
                                                      const float* __restrict__ w,
                                                      u16* __restrict__ Ct,
                                                      const float* __restrict__ bias,
                                                      const float* __restrict__ redB,
                                                      const float* __restrict__ gB,
                                                      const float* __restrict__ beB,
                                                      float invN,
                                                      float* __restrict__ partials) {
    constexpr int KT  = KDIM / 64;
    constexpr int NI  = COLT / 32;
    constexpr int ASZ = 128 * 64;            // u16 elements per A buffer
    constexpr int BSZ = COLT * 64;
    __shared__ u16 smem[2 * ASZ + 2 * BSZ];  // staging; overlaid by Cs+reds after loop
    __shared__ float sSc[MODE == 1 ? KDIM : 1];
    __shared__ float sSh[MODE == 1 ? KDIM : 1];

    int t   = threadIdx.x;
    int l   = t & 63;
    int wv  = t >> 6;
    int rl  = l >> 3;                    // staging row-in-group 0..7
    int cg  = ((l & 7) ^ rl) * 8;        // swizzled global chunk (elements)
    int mb0 = blockIdx.y * 128;
    int cb0 = blockIdx.x * COLT;
    int lm  = l & 15;
    int q   = l >> 4;
    int wm0 = (wv & 1) * 64;
    int wn0 = (wv >> 1) * (COLT / 2);

    const u16* Abase = A + (size_t)mb0 * KDIM;

    // MODE2 prologue: per-thread column interpolation params
    int vi0 = 0, vi1 = 0, vi2 = 0;
    float vw0 = 0.f, vw1 = 0.f, vw2 = 0.f;
    const u16* p2base = nullptr;
    if (MODE == 2) {
        int colg = cb0 + (t >> 2);
        vi0 = idx[colg * 3 + 0]; vi1 = idx[colg * 3 + 1]; vi2 = idx[colg * 3 + 2];
        vw0 = w[colg * 3 + 0];   vw1 = w[colg * 3 + 1];   vw2 = w[colg * 3 + 2];
        p2base = Bt + (size_t)(cb0 >> 13) * MM * C2;
    }
    if (MODE == 1) {
        // fold reduced BN0 stats into scale/shift (KDIM == 256 == blockDim)
        int by = t >> 7, chL = t & 127;
        const float* base = redB + (size_t)by * 8 * 256;
        float s = 0.f, s2 = 0.f;
#pragma unroll
        for (int i = 0; i < 8; ++i) {
            s  += base[i * 256 + chL];
            s2 += base[i * 256 + 128 + chL];
        }
        float mean = s * invN;
        float var  = fmaxf(s2 * invN - mean * mean, 0.f);
        float inv  = rsqrtf(var + BN_EPS);
        float sc   = gB[t] * inv;
        sSc[t] = sc;
        sSh[t] = beB[t] - mean * sc;
        __syncthreads();
    }

    auto stage = [&](int buf, int k0) {
#pragma unroll
        for (int iss = 0; iss < 4; ++iss) {              // A: 128 rows, DMA
            int row = wv * 32 + iss * 8;
            const u16* g = Abase + (size_t)(row + rl) * KDIM + k0 + cg;
            __builtin_amdgcn_global_load_lds(
                (const __attribute__((address_space(1))) unsigned int*)g,
                (__attribute__((address_space(3))) unsigned int*)(&smem[buf * ASZ + row * 64]),
                16, 0, 0);
        }
        if (MODE == 0) {
#pragma unroll
            for (int iss = 0; iss < COLT / 32; ++iss) {
                int row = wv * (COLT / 4) + iss * 8;
                const u16* g = Bt + (size_t)(cb0 + row + rl) * KDIM + k0 + cg;
                __builtin_amdgcn_global_load_lds(
                    (const __attribute__((address_space(1))) unsigned int*)g,
                    (__attribute__((address_space(3))) unsigned int*)(&smem[2 * ASZ + buf * BSZ + row * 64]),
                    16, 0, 0);
            }
        } else if (MODE == 1) {
            int row = t >> 2;                            // 0..63
            int kc  = (t & 3) * 16;
            const u16* gp = Bt + (size_t)(cb0 + row) * KDIM + k0 + kc;
            union { uint4 v; u16 u[8]; } lo, hi;
            lo.v = *(const uint4*)gp;
            hi.v = *(const uint4*)(gp + 8);
#pragma unroll
            for (int e = 0; e < 8; ++e) {
                float f0 = bf2f(lo.u[e]);
                lo.u[e] = f2bf(fmaxf(f0 * sSc[k0 + kc + e] + sSh[k0 + kc + e], 0.f));
                float f1 = bf2f(hi.u[e]);
                hi.u[e] = f2bf(fmaxf(f1 * sSc[k0 + kc + 8 + e] + sSh[k0 + kc + 8 + e], 0.f));
            }
            int c0 = kc >> 3;
            u16* dstB = &smem[2 * ASZ + buf * BSZ + row * 64];
            *(uint4*)&dstB[((c0)     ^ (row & 7)) * 8] = lo.v;
            *(uint4*)&dstB[((c0 + 1) ^ (row & 7)) * 8] = hi.v;
        } else {  // MODE 2
            if (k0 < C2) {
                int row = t >> 2;
                int kc  = (t & 3) * 16;
                const u16* bp = p2base + k0 + kc;
                const u16* r0p = bp + (size_t)vi0 * C2;
                const u16* r1p = bp + (size_t)vi1 * C2;
                const u16* r2p = bp + (size_t)vi2 * C2;
                union { uint4 v; u16 u[8]; } x0, x1, x2, y0, y1, y2, lo, hi;
                x0.v = *(const uint4*)r0p; y0.v = *(const uint4*)(r0p + 8);
                x1.v = *(const uint4*)r1p; y1.v = *(const uint4*)(r1p + 8);
                x2.v = *(const uint4*)r2p; y2.v = *(const uint4*)(r2p + 8);
#pragma unroll
                for (int e = 0; e < 8; ++e) {
                    lo.u[e] = f2bf(vw0 * bf2f(x0.u[e]) + vw1 * bf2f(x1.u[e]) + vw2 * bf2f(x2.u[e]));
                    hi.u[e] = f2bf(vw0 * bf2f(y0.u[e]) + vw1 * bf2f(y1.u[e]) + vw2 * bf2f(y2.u[e]));
                }
                int c0 = kc >> 3;
                u16* dstB = &smem[2 * ASZ + buf * BSZ + row * 64];
                *(uint4*)&dstB[((c0)     ^ (row & 7)) * 8] = lo.v;
                *(uint4*)&dstB[((c0 + 1) ^ (row & 7)) * 8] = hi.v;
            } else {
#pragma unroll
                for (int iss = 0; iss < COLT / 32; ++iss) {  // p1T DMA (K-contig)
                    int row = wv * (COLT / 4) + iss * 8;
                    const u16* g = p1T + (size_t)(cb0 + row + rl) * C1 + (k0 - C2) + cg;
                    __builtin_amdgcn_global_load_lds(
                        (const __attribute__((address_space(1))) unsigned int*)g,
                        (__attribute__((address_space(3))) unsigned int*)(&smem[2 * ASZ + buf * BSZ + row * 64]),
                        16, 0, 0);
                }
            }
        }
    };

    f32x4 acc[4][NI] = {};

    stage(0, 0);
    for (int kt = 0; kt < KT; ++kt) {
        __syncthreads();                                  // drains DMA + ds_writes
        if (kt + 1 < KT) stage((kt + 1) & 1, (kt + 1) * 64);
        const u16* As = &smem[(kt & 1) * ASZ];
        const u16* Bs = &smem[2 * ASZ + (kt & 1) * BSZ];
#pragma unroll
        for (int ks = 0; ks < 2; ++ks) {
            int csw = ((ks * 4 + q) ^ (lm & 7)) * 8;      // un-swizzle chunk offset
            short8 av[4], bv[NI];
#pragma unroll
            for (int mi = 0; mi < 4; ++mi)
                av[mi] = *(const short8*)&As[(wm0 + mi * 16 + lm) * 64 + csw];
#pragma unroll
            for (int ni = 0; ni < NI; ++ni)
                bv[ni] = *(const short8*)&Bs[(wn0 + ni * 16 + lm) * 64 + csw];
#pragma unroll
            for (int mi = 0; mi < 4; ++mi)
#pragma unroll
                for (int ni = 0; ni < NI; ++ni)
                    acc[mi][ni] = __builtin_amdgcn_mfma_f32_16x16x32_bf16(
                        av[mi], bv[ni], acc[mi][ni], 0, 0, 0);
        }
    }

    // ---- Epilogue (LDS overlay): Cs = COLT x 136 u16, reds = 256 floats ----
    u16*   Cs   = smem;                              // [colL*136 + m]
    float* reds = (float*)&smem[COLT * 136];         // [s*128 + chL]

    __syncthreads();                                  // all MFMA LDS reads done
    if (t < 256) reds[t] = 0.f;
    __syncthreads();

#pragma unroll
    for (int mi = 0; mi < 4; ++mi) {
        int chL = wm0 + mi * 16 + q * 4;             // local channel, 4 consecutive
        float bv4[4];
#pragma unroll
        for (int r = 0; r < 4; ++r) bv4[r] = bias[mb0 + chL + r];
        float s[4]  = {0.f, 0.f, 0.f, 0.f};
        float s2[4] = {0.f, 0.f, 0.f, 0.f};
#pragma unroll
        for (int ni = 0; ni < NI; ++ni) {
            int colL = wn0 + ni * 16 + lm;
            union { u16 u[4]; uint2 d; } pk;
#pragma unroll
            for (int r = 0; r < 4; ++r) {
                float v = acc[mi][ni][r] + bv4[r];
                s[r]  += v;
                s2[r] += v * v;
                pk.u[r] = f2bf(v);
            }
            *(uint2*)&Cs[colL * 136 + chL] = pk.d;
        }
#pragma unroll
        for (int r = 0; r < 4; ++r) {
            float a = s[r], b2 = s2[r];
#pragma unroll
            for (int off = 1; off < 16; off <<= 1) {
                a  += __shfl_xor(a, off, 64);
                b2 += __shfl_xor(b2, off, 64);
            }
            if (lm == 0) {
                atomicAdd(&reds[chL + r], a);          // LDS atomic (on-CU)
                atomicAdd(&reds[128 + chL + r], b2);
            }
        }
    }
    __syncthreads();

    // coalesced C-store: COLT rows x 128 m; each half-row = 64 u16 = 8 x uint4
    for (int u = t; u < COLT * 2; u += 256) {
        int c = u >> 1, h = u & 1;
        const u16* src = &Cs[c * 136 + h * 64];
        u16* dst = Ct + (size_t)(cb0 + c) * LDC + mb0 + h * 64;
#pragma unroll
        for (int jj = 0; jj < 8; ++jj)
            *(uint4*)(dst + jj * 8) = *(const uint4*)(src + jj * 8);
    }
    // one plain partial record per block
    partials[((size_t)blockIdx.y * gridDim.x + blockIdx.x) * 256 + t] = reds[t];
}

// ---------------------------------------------------------------------------
// K5a: stage-1 partial reduction: 16 blocks, block r sums `chunk` records.
__global__ __launch_bounds__(256) void reduce_partials_kernel(const float* __restrict__ in,
                                                              float* __restrict__ out,
                                                              int chunk) {
    int t = threadIdx.x, r = blockIdx.x;
    const float* base = in + (size_t)r * chunk * 256;
    float s = 0.f;
#pragma unroll 8
    for (int i = 0; i < chunk; ++i) s += base[(size_t)i * 256 + t];
    out[(size_t)r * 256 + t] = s;
}

// ---------------------------------------------------------------------------
// K8: final BN+ReLU on y1^T[col][c] (bf16) and transpose to out[b][c][n] (f32).
// Prologue folds red1 (16 records) + g1/be1 into scale/shift in LDS.
__global__ __launch_bounds__(256) void finalize_kernel(const u16* __restrict__ y1T,
                                                       const float* __restrict__ red1,
                                                       const float* __restrict__ g1,
                                                       const float* __restrict__ be1,
                                                       float invN,
                                                       float* __restrict__ out) {
    __shared__ float tile[64][129];
    __shared__ float sc[O1], sh[O1];
    int t  = threadIdx.x;
    int b  = blockIdx.y;
    int n0 = blockIdx.x * 64;

    if (t < O1) {
        float s = 0.f, s2 = 0.f;
#pragma unroll
        for (int i = 0; i < 16; ++i) {
            s  += red1[i * 256 + t];
            s2 += red1[i * 256 + 128 + t];
        }
        float mean = s * invN;
        float var  = fmaxf(s2 * invN - mean * mean, 0.f);
        float inv  = rsqrtf(var + BN_EPS);
        float scv  = g1[t] * inv;
        sc[t] = scv;
        sh[t] = be1[t] - mean * scv;
    }
    __syncthreads();

#pragma unroll
    for (int it = 0; it < 32; ++it) {
        int flat = it * 256 + t;
        int cl = flat >> 7;          // local col 0..63
        int c  = flat & 127;
        int col = b * NN + n0 + cl;
        float v = bf2f(y1T[(size_t)col * O1 + c]);
        tile[cl][c] = fmaxf(v * sc[c] + sh[c], 0.f);
    }
    __syncthreads();
#pragma unroll
    for (int it = 0; it < 32; ++it) {
        int flat = it * 256 + t;
        int c  = flat >> 6;          // channel 0..127
        int nl = flat & 63;
        out[(size_t)b * O1 * NN + (size_t)c * NN + n0 + nl] = tile[nl][c];
    }
}

// ---------------------------------------------------------------------------
extern "C" void kernel_launch(void* const* d_in, const int* in_sizes, int n_in,
                              void* d_out, int out_size, void* d_ws, size_t ws_size,
                              hipStream_t stream) {
    (void)in_sizes; (void)n_in; (void)out_size; (void)ws_size;

    const float* xyz1    = (const float*)d_in[0];
    const float* xyz2    = (const float*)d_in[1];
    const float* norm1   = (const float*)d_in[2];
    const float* norm2   = (const float*)d_in[3];
    const float* points1 = (const float*)d_in[4];
    const float* points2 = (const float*)d_in[5];
    const float* W0f     = (const float*)d_in[6];
    const float* b0      = (const float*)d_in[7];
    const float* g0      = (const float*)d_in[8];
    const float* be0     = (const float*)d_in[9];
    const float* W1f     = (const float*)d_in[10];
    const float* b1      = (const float*)d_in[11];
    const float* g1      = (const float*)d_in[12];
    const float* be1     = (const float*)d_in[13];
    float* out = (float*)d_out;

    // workspace carve-up (all 256B-aligned)
    char* w8 = (char*)d_ws;
    size_t off = 0;
    auto carve = [&](size_t bytes) { void* p = w8 + off; off += (bytes + 255) & ~(size_t)255; return p; };
    int*   idxW   = (int*)  carve((size_t)NCOL * 3 * sizeof(int));
    float* wW     = (float*)carve((size_t)NCOL * 3 * sizeof(float));
    u16*   p2T    = (u16*)  carve((size_t)BB * MM * C2 * 2);
    u16*   p1T    = (u16*)  carve((size_t)BB * NN * C1 * 2);
    u16*   W0b    = (u16*)  carve((size_t)O0 * CH0 * 2);
    u16*   W1b    = (u16*)  carve((size_t)O1 * O0 * 2);
    u16*   y0T    = (u16*)  carve((size_t)NCOL * O0 * 2);
    u16*   y1T    = (u16*)  carve((size_t)NCOL * O1 * 2);
    float* part0  = (float*)carve((size_t)1024 * 256 * sizeof(float)); // 1024 records
    float* part1  = (float*)carve((size_t)512 * 256 * sizeof(float));  // 512 records
    float* red0   = (float*)carve((size_t)16 * 256 * sizeof(float));
    float* red1   = (float*)carve((size_t)16 * 256 * sizeof(float));

    const float invN = 1.0f / (float)NCOL;

    prep_kernel<<<6656, 256, 0, stream>>>(points2, p2T, points1, p1T,
                                          W0f, W0b, W1f, W1b);

    three_nn_kernel<<<BB * (NN / 64), 256, 0, stream>>>(xyz1, xyz2, norm1, norm2, idxW, wW);

    // GEMM0 (MODE 2): interpolation fused into B staging; p1 channels via DMA
    gemm_bt_kernel<CH0, O0, 64, 2><<<dim3(NCOL / 64, O0 / 128), 256, 0, stream>>>(
        W0b, p2T, p1T, idxW, wW, y0T, b0, nullptr, nullptr, nullptr, invN, part0);
    reduce_partials_kernel<<<16, 256, 0, stream>>>(part0, red0, 64);

    // GEMM1 (MODE 1): fused BN0+ReLU on B; prologue folds red0+g0/be0
    gemm_bt_kernel<O0, O1, 64, 1><<<dim3(NCOL / 64, O1 / 128), 256, 0, stream>>>(
        W1b, y0T, nullptr, nullptr, nullptr, y1T, b1, red0, g0, be0, invN, part1);
    reduce_partials_kernel<<<16, 256, 0, stream>>>(part1, red1, 32);

    finalize_kernel<<<dim3(NN / 64, BB), 256, 0, stream>>>(y1T, red1, g1, be1, invN, out);
}

// Round 12
// 199.416 us; speedup vs baseline: 1.0716x; 1.0716x over previous
//
#include <hip/hip_runtime.h>
#include <hip/hip_bf16.h>
#include <cstdint>
#include <cstddef>

// Problem constants (B,N,M,C2,C1) = (4, 8192, 2048, 256, 128)
static constexpr int BB   = 4;
static constexpr int NN   = 8192;
static constexpr int MM   = 2048;
static constexpr int C1   = 128;
static constexpr int C2   = 256;
static constexpr int CH0  = C2 + C1;   // 384  (K of GEMM0)
static constexpr int O0   = 256;       // out channels layer 0
static constexpr int O1   = 128;       // out channels layer 1
static constexpr int NCOL = BB * NN;   // 32768 columns
static constexpr float BN_EPS = 1e-5f;

using u16 = unsigned short;
typedef __attribute__((ext_vector_type(8))) short short8;
typedef __attribute__((ext_vector_type(4))) float f32x4;

static __device__ __forceinline__ float bf2f(u16 u) {
    union { unsigned int i; float f; } v; v.i = ((unsigned int)u) << 16; return v.f;
}
static __device__ __forceinline__ u16 f2bf(float f) {
    union { float f; unsigned int i; } v; v.f = f;
    unsigned int r = (v.i + 0x7fffu + ((v.i >> 16) & 1u)) >> 16;
    return (u16)r;
}

// ---------------------------------------------------------------------------
// K1 (merged prep): blocks 0..2047 transpose points2 (256x2048 -> 2048x256),
// blocks 2048..6143 transpose points1 (128x8192 -> 8192x128),
// blocks 6144..6655 cast W0,W1 f32->bf16.
__global__ __launch_bounds__(256) void prep_kernel(const float* __restrict__ points2,
                                                   u16* __restrict__ p2T,
                                                   const float* __restrict__ points1,
                                                   u16* __restrict__ p1T,
                                                   const float* __restrict__ W0f,
                                                   u16* __restrict__ W0b,
                                                   const float* __restrict__ W1f,
                                                   u16* __restrict__ W1b) {
    __shared__ float tile[32][33];
    int id = blockIdx.x;
    int t  = threadIdx.x;
    if (id < 6144) {
        const float* in; u16* out; int R, C, b, c0, r0;
        if (id < 2048) {
            in = points2; out = p2T; R = C2; C = MM;
            b = id >> 9; int rem = id & 511;
            c0 = (rem & 63) * 32; r0 = (rem >> 6) * 32;
        } else {
            int id2 = id - 2048;
            in = points1; out = p1T; R = C1; C = NN;
            b = id2 >> 10; int rem = id2 & 1023;
            c0 = (rem & 255) * 32; r0 = (rem >> 8) * 32;
        }
        int tx = t & 31, ty = t >> 5;        // (32,8)
        const float* pin = in + (size_t)b * R * C;
        u16* pout = out + (size_t)b * R * C;
#pragma unroll
        for (int j = 0; j < 4; ++j) {
            int r = ty + j * 8;
            tile[r][tx] = pin[(size_t)(r0 + r) * C + (c0 + tx)];
        }
        __syncthreads();
#pragma unroll
        for (int j = 0; j < 4; ++j) {
            int c = ty + j * 8;
            pout[(size_t)(c0 + c) * R + (r0 + tx)] = f2bf(tile[tx][c]);
        }
    } else {
        int i = (id - 6144) * 256 + t;
        if (i < O0 * CH0) W0b[i] = f2bf(W0f[i]);
        else {
            int i2 = i - O0 * CH0;
            if (i2 < O1 * O0) W1b[i2] = f2bf(W1f[i2]);
        }
    }
}

// ---------------------------------------------------------------------------
// K2: 3-NN + combined (distance * normal) interpolation weights. f32 inputs.
// r10-proven configuration: ONE query per thread, 8 lanes/query stride-8 LDS
// scan over two 1024-point chunks, branchy sorted insert, 3-step shfl_xor
// merge with lexicographic (d, idx) tie-break (= top_k semantics).
// [r11 post-mortem: 2 queries/thread halved LDS reads but also halved wave
// count (16->8 waves/CU) -> net regression 48.9->65.7 us. This shape is the
// occupancy/reuse optimum of the family; VALU-issue floor ~34 us measured.]
__global__ __launch_bounds__(256) void three_nn_kernel(const float* __restrict__ xyz1,
                                                       const float* __restrict__ xyz2,
                                                       const float* __restrict__ norm1,
                                                       const float* __restrict__ norm2,
                                                       int* __restrict__ idxOut,
                                                       float* __restrict__ wOut) {
#pragma clang fp contract(off)
    constexpr int CH = 1024;             // points per LDS chunk
    __shared__ float4 pts[CH];
    int b    = blockIdx.x >> 8;          // 256 blocks of 32 queries per batch
    int nblk = blockIdx.x & 255;
    int t    = threadIdx.x;
    int j    = t & 7;                    // lane within the 8-thread query group

    int n = nblk * 32 + (t >> 3);
    const float* x1 = xyz1 + (size_t)b * 3 * NN;
    float qx = x1[n], qy = x1[NN + n], qz = x1[2 * NN + n];
    float qq = (qx * qx + qy * qy) + qz * qz;

    const float* x2 = xyz2 + (size_t)b * 3 * MM;

    float d0 = 3.4e38f, d1 = 3.4e38f, d2v = 3.4e38f;
    int   i0 = 0, i1 = 0, i2 = 0;

    for (int chunk = 0; chunk < MM / CH; ++chunk) {
        __syncthreads();                 // prior scan done before overwrite
        for (int i = t; i < CH; i += 256) {
            int m = chunk * CH + i;
            float px = x2[m];
            float py = x2[MM + m];
            float pz = x2[2 * MM + m];
            float pp = (px * px + py * py) + pz * pz;
            pts[i] = make_float4(px, py, pz, pp);
        }
        __syncthreads();

#pragma unroll 8
        for (int s = 0; s < CH / 8; ++s) {
            int ml = s * 8 + j;          // ascending per thread -> stable ties
            float4 P = pts[ml];
            float qp = (qx * P.x + qy * P.y) + qz * P.z;
            float d  = (qq + P.w) - 2.0f * qp;
            if (d < d2v) {
                int m = chunk * CH + ml;
                if (d < d1) {
                    if (d < d0) { d2v = d1; i2 = i1; d1 = d0; i1 = i0; d0 = d; i0 = m; }
                    else        { d2v = d1; i2 = i1; d1 = d;  i1 = m; }
                } else          { d2v = d;  i2 = m; }
            }
        }
    }

    // merge sorted triples across the 8 lanes of the group (lexicographic tie-break)
#pragma unroll
    for (int k = 1; k <= 4; k <<= 1) {
        float e0 = __shfl_xor(d0, k, 64), e1 = __shfl_xor(d1, k, 64), e2 = __shfl_xor(d2v, k, 64);
        int   f0 = __shfl_xor(i0, k, 64), f1 = __shfl_xor(i1, k, 64), f2 = __shfl_xor(i2, k, 64);
        float ed[3] = {e0, e1, e2}; int ef[3] = {f0, f1, f2};
#pragma unroll
        for (int e = 0; e < 3; ++e) {
            float dd = ed[e]; int ff = ef[e];
            bool b2 = (dd < d2v) || (dd == d2v && ff < i2);
            if (b2) {
                bool b1 = (dd < d1) || (dd == d1 && ff < i1);
                if (b1) {
                    d2v = d1; i2 = i1;
                    bool b0 = (dd < d0) || (dd == d0 && ff < i0);
                    if (b0) { d1 = d0; i1 = i0; d0 = dd; i0 = ff; }
                    else    { d1 = dd; i1 = ff; }
                } else { d2v = dd; i2 = ff; }
            }
        }
    }

    if (j == 0) {
        float s0 = sqrtf(fmaxf(d0, 1e-20f));
        float s1 = sqrtf(fmaxf(d1, 1e-20f));
        float s2 = sqrtf(fmaxf(d2v, 1e-20f));
        float r0 = 1.0f / fmaxf(s0, 1e-10f);
        float r1 = 1.0f / fmaxf(s1, 1e-10f);
        float r2 = 1.0f / fmaxf(s2, 1e-10f);
        float rs = (r0 + r1) + r2;
        float w0 = r0 / rs, w1 = r1 / rs, w2 = r2 / rs;

        const float* nm1 = norm1 + (size_t)b * 3 * NN;
        const float* nm2 = norm2 + (size_t)b * 3 * MM;
        float ax = nm1[n], ay = nm1[NN + n], az = nm1[2 * NN + n];
        float nd[3]; int ii[3] = {i0, i1, i2};
#pragma unroll
        for (int k = 0; k < 3; ++k) {
            int ik = ii[k];
            float dx = ax - nm2[ik];
            float dy = ay - nm2[MM + ik];
            float dz = az - nm2[2 * MM + ik];
            nd[k] = sqrtf((dx * dx + dy * dy) + dz * dz);
        }
        float m0 = 1.0f / fmaxf(nd[0], 1e-10f);
        float m1 = 1.0f / fmaxf(nd[1], 1e-10f);
        float m2 = 1.0f / fmaxf(nd[2], 1e-10f);
        float ms = (m0 + m1) + m2;

        int col = b * NN + n;
        idxOut[col * 3 + 0] = i0;
        idxOut[col * 3 + 1] = i1;
        idxOut[col * 3 + 2] = i2;
        wOut[col * 3 + 0] = w0 * (m0 / ms);
        wOut[col * 3 + 1] = w1 * (m1 / ms);
        wOut[col * 3 + 2] = w2 * (m2 / ms);
    }
}

// ---------------------------------------------------------------------------
// K4/K6: GEMM  C^T[col][m] = sum_k A[m][k] * Bsrc[col][k] + bias[m]
// 128 rows x COLT cols, BK=64, 256 threads, 16x16x32 bf16 MFMA.
// A staging: async global_load_lds (16B/lane), XOR-swizzled, double-buffered.
// B staging by MODE:
//   0: DMA from Bt (K-contiguous B^T).
//   1: VGPR path from Bt applying relu(f*sc+sh); sc/sh folded in PROLOGUE
//      from 16-record reduced stats redB + gB/beB (fused BN+ReLU).
//   2: k<256: VGPR gather-interpolate from p2T (Bt) using idx/w (fused
//      three_interpolate; kills the xT materialization); k>=256: DMA p1T.
// BN stats out: shuffle-reduce -> LDS atomics -> one partial record/block.
template <int KDIM, int LDC, int COLT, int MODE>
__global__ __launch_bounds__(256) void gemm_bt_kernel(const u16* __restrict__ A,
                                                      const u16* __restrict__ Bt,
                                                      const u16* __restrict__ p1T,
                                                      const int* __restrict__ idx,
                                                      const float* __restrict__ w,
                                                      u16* __restrict__ Ct,
                                                      const float* __restrict__ bias,
                                                      const float* __restrict__ redB,
                                                      const float* __restrict__ gB,
                                                      const float* __restrict__ beB,
                                                      float invN,
                                                      float* __restrict__ partials) {
    constexpr int KT  = KDIM / 64;
    constexpr int NI  = COLT / 32;
    constexpr int ASZ = 128 * 64;            // u16 elements per A buffer
    constexpr int BSZ = COLT * 64;
    __shared__ u16 smem[2 * ASZ + 2 * BSZ];  // staging; overlaid by Cs+reds after loop
    __shared__ float sSc[MODE == 1 ? KDIM : 1];
    __shared__ float sSh[MODE == 1 ? KDIM : 1];

    int t   = threadIdx.x;
    int l   = t & 63;
    int wv  = t >> 6;
    int rl  = l >> 3;                    // staging row-in-group 0..7
    int cg  = ((l & 7) ^ rl) * 8;        // swizzled global chunk (elements)
    int mb0 = blockIdx.y * 128;
    int cb0 = blockIdx.x * COLT;
    int lm  = l & 15;
    int q   = l >> 4;
    int wm0 = (wv & 1) * 64;
    int wn0 = (wv >> 1) * (COLT / 2);

    const u16* Abase = A + (size_t)mb0 * KDIM;

    // MODE2 prologue: per-thread column interpolation params
    int vi0 = 0, vi1 = 0, vi2 = 0;
    float vw0 = 0.f, vw1 = 0.f, vw2 = 0.f;
    const u16* p2base = nullptr;
    if (MODE == 2) {
        int colg = cb0 + (t >> 2);
        vi0 = idx[colg * 3 + 0]; vi1 = idx[colg * 3 + 1]; vi2 = idx[colg * 3 + 2];
        vw0 = w[colg * 3 + 0];   vw1 = w[colg * 3 + 1];   vw2 = w[colg * 3 + 2];
        p2base = Bt + (size_t)(cb0 >> 13) * MM * C2;
    }
    if (MODE == 1) {
        // fold reduced BN0 stats into scale/shift (KDIM == 256 == blockDim)
        int by = t >> 7, chL = t & 127;
        const float* base = redB + (size_t)by * 8 * 256;
        float s = 0.f, s2 = 0.f;
#pragma unroll
        for (int i = 0; i < 8; ++i) {
            s  += base[i * 256 + chL];
            s2 += base[i * 256 + 128 + chL];
        }
        float mean = s * invN;
        float var  = fmaxf(s2 * invN - mean * mean, 0.f);
        float inv  = rsqrtf(var + BN_EPS);
        float sc   = gB[t] * inv;
        sSc[t] = sc;
        sSh[t] = beB[t] - mean * sc;
        __syncthreads();
    }

    auto stage = [&](int buf, int k0) {
#pragma unroll
        for (int iss = 0; iss < 4; ++iss) {              // A: 128 rows, DMA
            int row = wv * 32 + iss * 8;
            const u16* g = Abase + (size_t)(row + rl) * KDIM + k0 + cg;
            __builtin_amdgcn_global_load_lds(
                (const __attribute__((address_space(1))) unsigned int*)g,
                (__attribute__((address_space(3))) unsigned int*)(&smem[buf * ASZ + row * 64]),
                16, 0, 0);
        }
        if (MODE == 0) {
#pragma unroll
            for (int iss = 0; iss < COLT / 32; ++iss) {
                int row = wv * (COLT / 4) + iss * 8;
                const u16* g = Bt + (size_t)(cb0 + row + rl) * KDIM + k0 + cg;
                __builtin_amdgcn_global_load_lds(
                    (const __attribute__((address_space(1))) unsigned int*)g,
                    (__attribute__((address_space(3))) unsigned int*)(&smem[2 * ASZ + buf * BSZ + row * 64]),
                    16, 0, 0);
            }
        } else if (MODE == 1) {
            int row = t >> 2;                            // 0..63
            int kc  = (t & 3) * 16;
            const u16* gp = Bt + (size_t)(cb0 + row) * KDIM + k0 + kc;
            union { uint4 v; u16 u[8]; } lo, hi;
            lo.v = *(const uint4*)gp;
            hi.v = *(const uint4*)(gp + 8);
#pragma unroll
            for (int e = 0; e < 8; ++e) {
                float f0 = bf2f(lo.u[e]);
                lo.u[e] = f2bf(fmaxf(f0 * sSc[k0 + kc + e] + sSh[k0 + kc + e], 0.f));
                float f1 = bf2f(hi.u[e]);
                hi.u[e] = f2bf(fmaxf(f1 * sSc[k0 + kc + 8 + e] + sSh[k0 + kc + 8 + e], 0.f));
            }
            int c0 = kc >> 3;
            u16* dstB = &smem[2 * ASZ + buf * BSZ + row * 64];
            *(uint4*)&dstB[((c0)     ^ (row & 7)) * 8] = lo.v;
            *(uint4*)&dstB[((c0 + 1) ^ (row & 7)) * 8] = hi.v;
        } else {  // MODE 2
            if (k0 < C2) {
                int row = t >> 2;
                int kc  = (t & 3) * 16;
                const u16* bp = p2base + k0 + kc;
                const u16* r0p = bp + (size_t)vi0 * C2;
                const u16* r1p = bp + (size_t)vi1 * C2;
                const u16* r2p = bp + (size_t)vi2 * C2;
                union { uint4 v; u16 u[8]; } x0, x1, x2, y0, y1, y2, lo, hi;
                x0.v = *(const uint4*)r0p; y0.v = *(const uint4*)(r0p + 8);
                x1.v = *(const uint4*)r1p; y1.v = *(const uint4*)(r1p + 8);
                x2.v = *(const uint4*)r2p; y2.v = *(const uint4*)(r2p + 8);
#pragma unroll
                for (int e = 0; e < 8; ++e) {
                    lo.u[e] = f2bf(vw0 * bf2f(x0.u[e]) + vw1 * bf2f(x1.u[e]) + vw2 * bf2f(x2.u[e]));
                    hi.u[e] = f2bf(vw0 * bf2f(y0.u[e]) + vw1 * bf2f(y1.u[e]) + vw2 * bf2f(y2.u[e]));
                }
                int c0 = kc >> 3;
                u16* dstB = &smem[2 * ASZ + buf * BSZ + row * 64];
                *(uint4*)&dstB[((c0)     ^ (row & 7)) * 8] = lo.v;
                *(uint4*)&dstB[((c0 + 1) ^ (row & 7)) * 8] = hi.v;
            } else {
#pragma unroll
                for (int iss = 0; iss < COLT / 32; ++iss) {  // p1T DMA (K-contig)
                    int row = wv * (COLT / 4) + iss * 8;
                    const u16* g = p1T + (size_t)(cb0 + row + rl) * C1 + (k0 - C2) + cg;
                    __builtin_amdgcn_global_load_lds(
                        (const __attribute__((address_space(1))) unsigned int*)g,
                        (__attribute__((address_space(3))) unsigned int*)(&smem[2 * ASZ + buf * BSZ + row * 64]),
                        16, 0, 0);
                }
            }
        }
    };

    f32x4 acc[4][NI] = {};

    stage(0, 0);
    for (int kt = 0; kt < KT; ++kt) {
        __syncthreads();                                  // drains DMA + ds_writes
        if (kt + 1 < KT) stage((kt + 1) & 1, (kt + 1) * 64);
        const u16* As = &smem[(kt & 1) * ASZ];
        const u16* Bs = &smem[2 * ASZ + (kt & 1) * BSZ];
#pragma unroll
        for (int ks = 0; ks < 2; ++ks) {
            int csw = ((ks * 4 + q) ^ (lm & 7)) * 8;      // un-swizzle chunk offset
            short8 av[4], bv[NI];
#pragma unroll
            for (int mi = 0; mi < 4; ++mi)
                av[mi] = *(const short8*)&As[(wm0 + mi * 16 + lm) * 64 + csw];
#pragma unroll
            for (int ni = 0; ni < NI; ++ni)
                bv[ni] = *(const short8*)&Bs[(wn0 + ni * 16 + lm) * 64 + csw];
#pragma unroll
            for (int mi = 0; mi < 4; ++mi)
#pragma unroll
                for (int ni = 0; ni < NI; ++ni)
                    acc[mi][ni] = __builtin_amdgcn_mfma_f32_16x16x32_bf16(
                        av[mi], bv[ni], acc[mi][ni], 0, 0, 0);
        }
    }

    // ---- Epilogue (LDS overlay): Cs = COLT x 136 u16, reds = 256 floats ----
    u16*   Cs   = smem;                              // [colL*136 + m]
    float* reds = (float*)&smem[COLT * 136];         // [s*128 + chL]

    __syncthreads();                                  // all MFMA LDS reads done
    if (t < 256) reds[t] = 0.f;
    __syncthreads();

#pragma unroll
    for (int mi = 0; mi < 4; ++mi) {
        int chL = wm0 + mi * 16 + q * 4;             // local channel, 4 consecutive
        float bv4[4];
#pragma unroll
        for (int r = 0; r < 4; ++r) bv4[r] = bias[mb0 + chL + r];
        float s[4]  = {0.f, 0.f, 0.f, 0.f};
        float s2[4] = {0.f, 0.f, 0.f, 0.f};
#pragma unroll
        for (int ni = 0; ni < NI; ++ni) {
            int colL = wn0 + ni * 16 + lm;
            union { u16 u[4]; uint2 d; } pk;
#pragma unroll
            for (int r = 0; r < 4; ++r) {
                float v = acc[mi][ni][r] + bv4[r];
                s[r]  += v;
                s2[r] += v * v;
                pk.u[r] = f2bf(v);
            }
            *(uint2*)&Cs[colL * 136 + chL] = pk.d;
        }
#pragma unroll
        for (int r = 0; r < 4; ++r) {
            float a = s[r], b2 = s2[r];
#pragma unroll
            for (int off = 1; off < 16; off <<= 1) {
                a  += __shfl_xor(a, off, 64);
                b2 += __shfl_xor(b2, off, 64);
            }
            if (lm == 0) {
                atomicAdd(&reds[chL + r], a);          // LDS atomic (on-CU)
                atomicAdd(&reds[128 + chL + r], b2);
            }
        }
    }
    __syncthreads();

    // coalesced C-store: COLT rows x 128 m; each half-row = 64 u16 = 8 x uint4
    for (int u = t; u < COLT * 2; u += 256) {
        int c = u >> 1, h = u & 1;
        const u16* src = &Cs[c * 136 + h * 64];
        u16* dst = Ct + (size_t)(cb0 + c) * LDC + mb0 + h * 64;
#pragma unroll
        for (int jj = 0; jj < 8; ++jj)
            *(uint4*)(dst + jj * 8) = *(const uint4*)(src + jj * 8);
    }
    // one plain partial record per block
    partials[((size_t)blockIdx.y * gridDim.x + blockIdx.x) * 256 + t] = reds[t];
}

// ---------------------------------------------------------------------------
// K5a: stage-1 partial reduction: 16 blocks, block r sums `chunk` records.
__global__ __launch_bounds__(256) void reduce_partials_kernel(const float* __restrict__ in,
                                                              float* __restrict__ out,
                                                              int chunk) {
    int t = threadIdx.x, r = blockIdx.x;
    const float* base = in + (size_t)r * chunk * 256;
    float s = 0.f;
#pragma unroll 8
    for (int i = 0; i < chunk; ++i) s += base[(size_t)i * 256 + t];
    out[(size_t)r * 256 + t] = s;
}

// ---------------------------------------------------------------------------
// K8: final BN+ReLU on y1^T[col][c] (bf16) and transpose to out[b][c][n] (f32).
// Prologue folds red1 (16 records) + g1/be1 into scale/shift in LDS.
__global__ __launch_bounds__(256) void finalize_kernel(const u16* __restrict__ y1T,
                                                       const float* __restrict__ red1,
                                                       const float* __restrict__ g1,
                                                       const float* __restrict__ be1,
                                                       float invN,
                                                       float* __restrict__ out) {
    __shared__ float tile[64][129];
    __shared__ float sc[O1], sh[O1];
    int t  = threadIdx.x;
    int b  = blockIdx.y;
    int n0 = blockIdx.x * 64;

    if (t < O1) {
        float s = 0.f, s2 = 0.f;
#pragma unroll
        for (int i = 0; i < 16; ++i) {
            s  += red1[i * 256 + t];
            s2 += red1[i * 256 + 128 + t];
        }
        float mean = s * invN;
        float var  = fmaxf(s2 * invN - mean * mean, 0.f);
        float inv  = rsqrtf(var + BN_EPS);
        float scv  = g1[t] * inv;
        sc[t] = scv;
        sh[t] = be1[t] - mean * scv;
    }
    __syncthreads();

#pragma unroll
    for (int it = 0; it < 32; ++it) {
        int flat = it * 256 + t;
        int cl = flat >> 7;          // local col 0..63
        int c  = flat & 127;
        int col = b * NN + n0 + cl;
        float v = bf2f(y1T[(size_t)col * O1 + c]);
        tile[cl][c] = fmaxf(v * sc[c] + sh[c], 0.f);
    }
    __syncthreads();
#pragma unroll
    for (int it = 0; it < 32; ++it) {
        int flat = it * 256 + t;
        int c  = flat >> 6;          // channel 0..127
        int nl = flat & 63;
        out[(size_t)b * O1 * NN + (size_t)c * NN + n0 + nl] = tile[nl][c];
    }
}

// ---------------------------------------------------------------------------
extern "C" void kernel_launch(void* const* d_in, const int* in_sizes, int n_in,
                              void* d_out, int out_size, void* d_ws, size_t ws_size,
                              hipStream_t stream) {
    (void)in_sizes; (void)n_in; (void)out_size; (void)ws_size;

    const float* xyz1    = (const float*)d_in[0];
    const float* xyz2    = (const float*)d_in[1];
    const float* norm1   = (const float*)d_in[2];
    const float* norm2   = (const float*)d_in[3];
    const float* points1 = (const float*)d_in[4];
    const float* points2 = (const float*)d_in[5];
    const float* W0f     = (const float*)d_in[6];
    const float* b0      = (const float*)d_in[7];
    const float* g0      = (const float*)d_in[8];
    const float* be0     = (const float*)d_in[9];
    const float* W1f     = (const float*)d_in[10];
    const float* b1      = (const float*)d_in[11];
    const float* g1      = (const float*)d_in[12];
    const float* be1     = (const float*)d_in[13];
    float* out = (float*)d_out;

    // workspace carve-up (all 256B-aligned)
    char* w8 = (char*)d_ws;
    size_t off = 0;
    auto carve = [&](size_t bytes) { void* p = w8 + off; off += (bytes + 255) & ~(size_t)255; return p; };
    int*   idxW   = (int*)  carve((size_t)NCOL * 3 * sizeof(int));
    float* wW     = (float*)carve((size_t)NCOL * 3 * sizeof(float));
    u16*   p2T    = (u16*)  carve((size_t)BB * MM * C2 * 2);
    u16*   p1T    = (u16*)  carve((size_t)BB * NN * C1 * 2);
    u16*   W0b    = (u16*)  carve((size_t)O0 * CH0 * 2);
    u16*   W1b    = (u16*)  carve((size_t)O1 * O0 * 2);
    u16*   y0T    = (u16*)  carve((size_t)NCOL * O0 * 2);
    u16*   y1T    = (u16*)  carve((size_t)NCOL * O1 * 2);
    float* part0  = (float*)carve((size_t)1024 * 256 * sizeof(float)); // 1024 records
    float* part1  = (float*)carve((size_t)512 * 256 * sizeof(float));  // 512 records
    float* red0   = (float*)carve((size_t)16 * 256 * sizeof(float));
    float* red1   = (float*)carve((size_t)16 * 256 * sizeof(float));

    const float invN = 1.0f / (float)NCOL;

    prep_kernel<<<6656, 256, 0, stream>>>(points2, p2T, points1, p1T,
                                          W0f, W0b, W1f, W1b);

    three_nn_kernel<<<BB * (NN / 32), 256, 0, stream>>>(xyz1, xyz2, norm1, norm2, idxW, wW);

    // GEMM0 (MODE 2): interpolation fused into B staging; p1 channels via DMA
    gemm_bt_kernel<CH0, O0, 64, 2><<<dim3(NCOL / 64, O0 / 128), 256, 0, stream>>>(
        W0b, p2T, p1T, idxW, wW, y0T, b0, nullptr, nullptr, nullptr, invN, part0);
    reduce_partials_kernel<<<16, 256, 0, stream>>>(part0, red0, 64);

    // GEMM1 (MODE 1): fused BN0+ReLU on B; prologue folds red0+g0/be0
    gemm_bt_kernel<O0, O1, 64, 1><<<dim3(NCOL / 64, O1 / 128), 256, 0, stream>>>(
        W1b, y0T, nullptr, nullptr, nullptr, y1T, b1, red0, g0, be0, invN, part1);
    reduce_partials_kernel<<<16, 256, 0, stream>>>(part1, red1, 32);

    finalize_kernel<<<dim3(NN / 64, BB), 256, 0, stream>>>(y1T, red1, g1, be1, invN, out);
}

// Round 13
// 189.921 us; speedup vs baseline: 1.1252x; 1.0500x over previous
//
#include <hip/hip_runtime.h>
#include <hip/hip_bf16.h>
#include <cstdint>
#include <cstddef>

// Problem constants (B,N,M,C2,C1) = (4, 8192, 2048, 256, 128)
static constexpr int BB   = 4;
static constexpr int NN   = 8192;
static constexpr int MM   = 2048;
static constexpr int C1   = 128;
static constexpr int C2   = 256;
static constexpr int CH0  = C2 + C1;   // 384  (K of GEMM0)
static constexpr int O0   = 256;       // out channels layer 0
static constexpr int O1   = 128;       // out channels layer 1
static constexpr int NCOL = BB * NN;   // 32768 columns
static constexpr float BN_EPS = 1e-5f;

// BN-stats super-records (atomicAdd targets; depth <= 16 per address)
static constexpr int REC0 = 64;        // per y-half for gemm0 (2 halves)
static constexpr int REC1 = 32;        // gemm1

using u16 = unsigned short;
typedef __attribute__((ext_vector_type(8))) short short8;
typedef __attribute__((ext_vector_type(4))) float f32x4;

static __device__ __forceinline__ float bf2f(u16 u) {
    union { unsigned int i; float f; } v; v.i = ((unsigned int)u) << 16; return v.f;
}
static __device__ __forceinline__ u16 f2bf(float f) {
    union { float f; unsigned int i; } v; v.f = f;
    unsigned int r = (v.i + 0x7fffu + ((v.i >> 16) & 1u)) >> 16;
    return (u16)r;
}

// ---------------------------------------------------------------------------
// K1 (fused pre-stage): blocks [0,1024) = 3-NN (r12-proven config, 32 q/block,
// 8 lanes/query); [1024,7680) = transposes + weight casts; [7680,7840) = zero
// the BN-stats super-records (atomicAdd targets, ws is 0xAA-poisoned).
__global__ __launch_bounds__(256) void fused_pre_kernel(
        const float* __restrict__ xyz1,  const float* __restrict__ xyz2,
        const float* __restrict__ norm1, const float* __restrict__ norm2,
        int* __restrict__ idxOut, float* __restrict__ wOut,
        const float* __restrict__ points2, u16* __restrict__ p2T,
        const float* __restrict__ points1, u16* __restrict__ p1T,
        const float* __restrict__ W0f, u16* __restrict__ W0b,
        const float* __restrict__ W1f, u16* __restrict__ W1b,
        float* __restrict__ part0, float* __restrict__ part1) {
#pragma clang fp contract(off)
    __shared__ union { float4 pts[1024]; float tile[32][33]; } sm;
    int id = blockIdx.x;
    int t  = threadIdx.x;

    if (id >= 7680) {                       // ---- zero super-records ----
        int flat = (id - 7680) * 256 + t;   // 160*256 = 40960 floats
        if (flat < 2 * REC0 * 256) part0[flat] = 0.f;
        else part1[flat - 2 * REC0 * 256] = 0.f;
        return;
    }
    if (id >= 1024) {                       // ---- prep: transpose / cast ----
        int pid = id - 1024;
        if (pid < 6144) {
            const float* in; u16* out; int R, C, b, c0, r0;
            if (pid < 2048) {
                in = points2; out = p2T; R = C2; C = MM;
                b = pid >> 9; int rem = pid & 511;
                c0 = (rem & 63) * 32; r0 = (rem >> 6) * 32;
            } else {
                int id2 = pid - 2048;
                in = points1; out = p1T; R = C1; C = NN;
                b = id2 >> 10; int rem = id2 & 1023;
                c0 = (rem & 255) * 32; r0 = (rem >> 8) * 32;
            }
            int tx = t & 31, ty = t >> 5;
            const float* pin = in + (size_t)b * R * C;
            u16* pout = out + (size_t)b * R * C;
#pragma unroll
            for (int j = 0; j < 4; ++j) {
                int r = ty + j * 8;
                sm.tile[r][tx] = pin[(size_t)(r0 + r) * C + (c0 + tx)];
            }
            __syncthreads();
#pragma unroll
            for (int j = 0; j < 4; ++j) {
                int c = ty + j * 8;
                pout[(size_t)(c0 + c) * R + (r0 + tx)] = f2bf(sm.tile[tx][c]);
            }
        } else {
            int i = (pid - 6144) * 256 + t;
            if (i < O0 * CH0) W0b[i] = f2bf(W0f[i]);
            else {
                int i2 = i - O0 * CH0;
                if (i2 < O1 * O0) W1b[i2] = f2bf(W1f[i2]);
            }
        }
        return;
    }

    // ---- 3-NN (bit-identical to r12) ----
    int b    = id >> 8;                  // 256 blocks of 32 queries per batch
    int nblk = id & 255;
    int j    = t & 7;                    // lane within the 8-thread query group

    int n = nblk * 32 + (t >> 3);
    const float* x1 = xyz1 + (size_t)b * 3 * NN;
    float qx = x1[n], qy = x1[NN + n], qz = x1[2 * NN + n];
    float qq = (qx * qx + qy * qy) + qz * qz;

    const float* x2 = xyz2 + (size_t)b * 3 * MM;

    float d0 = 3.4e38f, d1 = 3.4e38f, d2v = 3.4e38f;
    int   i0 = 0, i1 = 0, i2 = 0;

    for (int chunk = 0; chunk < MM / 1024; ++chunk) {
        __syncthreads();
        for (int i = t; i < 1024; i += 256) {
            int m = chunk * 1024 + i;
            float px = x2[m];
            float py = x2[MM + m];
            float pz = x2[2 * MM + m];
            float pp = (px * px + py * py) + pz * pz;
            sm.pts[i] = make_float4(px, py, pz, pp);
        }
        __syncthreads();

#pragma unroll 8
        for (int s = 0; s < 1024 / 8; ++s) {
            int ml = s * 8 + j;          // ascending per thread -> stable ties
            float4 P = sm.pts[ml];
            float qp = (qx * P.x + qy * P.y) + qz * P.z;
            float d  = (qq + P.w) - 2.0f * qp;
            if (d < d2v) {
                int m = chunk * 1024 + ml;
                if (d < d1) {
                    if (d < d0) { d2v = d1; i2 = i1; d1 = d0; i1 = i0; d0 = d; i0 = m; }
                    else        { d2v = d1; i2 = i1; d1 = d;  i1 = m; }
                } else          { d2v = d;  i2 = m; }
            }
        }
    }

    // merge sorted triples across the 8 lanes (lexicographic tie-break)
#pragma unroll
    for (int k = 1; k <= 4; k <<= 1) {
        float e0 = __shfl_xor(d0, k, 64), e1 = __shfl_xor(d1, k, 64), e2 = __shfl_xor(d2v, k, 64);
        int   f0 = __shfl_xor(i0, k, 64), f1 = __shfl_xor(i1, k, 64), f2 = __shfl_xor(i2, k, 64);
        float ed[3] = {e0, e1, e2}; int ef[3] = {f0, f1, f2};
#pragma unroll
        for (int e = 0; e < 3; ++e) {
            float dd = ed[e]; int ff = ef[e];
            bool b2 = (dd < d2v) || (dd == d2v && ff < i2);
            if (b2) {
                bool b1 = (dd < d1) || (dd == d1 && ff < i1);
                if (b1) {
                    d2v = d1; i2 = i1;
                    bool b0 = (dd < d0) || (dd == d0 && ff < i0);
                    if (b0) { d1 = d0; i1 = i0; d0 = dd; i0 = ff; }
                    else    { d1 = dd; i1 = ff; }
                } else { d2v = dd; i2 = ff; }
            }
        }
    }

    if (j == 0) {
        float s0 = sqrtf(fmaxf(d0, 1e-20f));
        float s1 = sqrtf(fmaxf(d1, 1e-20f));
        float s2 = sqrtf(fmaxf(d2v, 1e-20f));
        float r0 = 1.0f / fmaxf(s0, 1e-10f);
        float r1 = 1.0f / fmaxf(s1, 1e-10f);
        float r2 = 1.0f / fmaxf(s2, 1e-10f);
        float rs = (r0 + r1) + r2;
        float w0 = r0 / rs, w1 = r1 / rs, w2 = r2 / rs;

        const float* nm1 = norm1 + (size_t)b * 3 * NN;
        const float* nm2 = norm2 + (size_t)b * 3 * MM;
        float ax = nm1[n], ay = nm1[NN + n], az = nm1[2 * NN + n];
        float nd[3]; int ii[3] = {i0, i1, i2};
#pragma unroll
        for (int k = 0; k < 3; ++k) {
            int ik = ii[k];
            float dx = ax - nm2[ik];
            float dy = ay - nm2[MM + ik];
            float dz = az - nm2[2 * MM + ik];
            nd[k] = sqrtf((dx * dx + dy * dy) + dz * dz);
        }
        float m0 = 1.0f / fmaxf(nd[0], 1e-10f);
        float m1 = 1.0f / fmaxf(nd[1], 1e-10f);
        float m2 = 1.0f / fmaxf(nd[2], 1e-10f);
        float ms = (m0 + m1) + m2;

        int col = b * NN + n;
        idxOut[col * 3 + 0] = i0;
        idxOut[col * 3 + 1] = i1;
        idxOut[col * 3 + 2] = i2;
        wOut[col * 3 + 0] = w0 * (m0 / ms);
        wOut[col * 3 + 1] = w1 * (m1 / ms);
        wOut[col * 3 + 2] = w2 * (m2 / ms);
    }
}

// ---------------------------------------------------------------------------
// K4/K6: GEMM  C^T[col][m] = sum_k A[m][k] * Bsrc[col][k] + bias[m]
// 128 rows x COLT cols, BK=64, 256 threads, 16x16x32 bf16 MFMA.
// A staging: async global_load_lds (16B/lane), XOR-swizzled, double-buffered.
// B staging by MODE:
//   1: VGPR path from Bt applying relu(f*sc+sh); sc/sh folded in PROLOGUE
//      from REC0 super-records (part0) + gB/beB (fused BN+ReLU).
//   2: k<256: VGPR gather-interpolate from p2T using idx/w (fused
//      three_interpolate); k>=256: DMA p1T.
// BN stats out: shuffle-reduce -> LDS atomics -> atomicAdd into super-record
// (contention depth <=16; part0/part1 pre-zeroed by fused_pre_kernel).
template <int KDIM, int LDC, int COLT, int MODE>
__global__ __launch_bounds__(256) void gemm_bt_kernel(const u16* __restrict__ A,
                                                      const u16* __restrict__ Bt,
                                                      const u16* __restrict__ p1T,
                                                      const int* __restrict__ idx,
                                                      const float* __restrict__ w,
                                                      u16* __restrict__ Ct,
                                                      const float* __restrict__ bias,
                                                      const float* __restrict__ redB,
                                                      const float* __restrict__ gB,
                                                      const float* __restrict__ beB,
                                                      float invN,
                                                      float* __restrict__ partials) {
    constexpr int KT  = KDIM / 64;
    constexpr int NI  = COLT / 32;
    constexpr int ASZ = 128 * 64;            // u16 elements per A buffer
    constexpr int BSZ = COLT * 64;
    __shared__ u16 smem[2 * ASZ + 2 * BSZ];  // staging; overlaid by Cs+reds after loop
    __shared__ float sSc[MODE == 1 ? KDIM : 1];
    __shared__ float sSh[MODE == 1 ? KDIM : 1];

    int t   = threadIdx.x;
    int l   = t & 63;
    int wv  = t >> 6;
    int rl  = l >> 3;                    // staging row-in-group 0..7
    int cg  = ((l & 7) ^ rl) * 8;        // swizzled global chunk (elements)
    int mb0 = blockIdx.y * 128;
    int cb0 = blockIdx.x * COLT;
    int lm  = l & 15;
    int q   = l >> 4;
    int wm0 = (wv & 1) * 64;
    int wn0 = (wv >> 1) * (COLT / 2);

    const u16* Abase = A + (size_t)mb0 * KDIM;

    // MODE2 prologue: per-thread column interpolation params
    int vi0 = 0, vi1 = 0, vi2 = 0;
    float vw0 = 0.f, vw1 = 0.f, vw2 = 0.f;
    const u16* p2base = nullptr;
    if (MODE == 2) {
        int colg = cb0 + (t >> 2);
        vi0 = idx[colg * 3 + 0]; vi1 = idx[colg * 3 + 1]; vi2 = idx[colg * 3 + 2];
        vw0 = w[colg * 3 + 0];   vw1 = w[colg * 3 + 1];   vw2 = w[colg * 3 + 2];
        p2base = Bt + (size_t)(cb0 >> 13) * MM * C2;
    }
    if (MODE == 1) {
        // fold BN0 super-record stats into scale/shift (KDIM == 256 == blockDim)
        int by = t >> 7, chL = t & 127;
        const float* base = redB + (size_t)by * REC0 * 256;
        float s = 0.f, s2 = 0.f;
#pragma unroll 8
        for (int i = 0; i < REC0; ++i) {
            s  += base[i * 256 + chL];
            s2 += base[i * 256 + 128 + chL];
        }
        float mean = s * invN;
        float var  = fmaxf(s2 * invN - mean * mean, 0.f);
        float inv  = rsqrtf(var + BN_EPS);
        float sc   = gB[t] * inv;
        sSc[t] = sc;
        sSh[t] = beB[t] - mean * sc;
        __syncthreads();
    }

    auto stage = [&](int buf, int k0) {
#pragma unroll
        for (int iss = 0; iss < 4; ++iss) {              // A: 128 rows, DMA
            int row = wv * 32 + iss * 8;
            const u16* g = Abase + (size_t)(row + rl) * KDIM + k0 + cg;
            __builtin_amdgcn_global_load_lds(
                (const __attribute__((address_space(1))) unsigned int*)g,
                (__attribute__((address_space(3))) unsigned int*)(&smem[buf * ASZ + row * 64]),
                16, 0, 0);
        }
        if (MODE == 1) {
            int row = t >> 2;                            // 0..63
            int kc  = (t & 3) * 16;
            const u16* gp = Bt + (size_t)(cb0 + row) * KDIM + k0 + kc;
            union { uint4 v; u16 u[8]; } lo, hi;
            lo.v = *(const uint4*)gp;
            hi.v = *(const uint4*)(gp + 8);
#pragma unroll
            for (int e = 0; e < 8; ++e) {
                float f0 = bf2f(lo.u[e]);
                lo.u[e] = f2bf(fmaxf(f0 * sSc[k0 + kc + e] + sSh[k0 + kc + e], 0.f));
                float f1 = bf2f(hi.u[e]);
                hi.u[e] = f2bf(fmaxf(f1 * sSc[k0 + kc + 8 + e] + sSh[k0 + kc + 8 + e], 0.f));
            }
            int c0 = kc >> 3;
            u16* dstB = &smem[2 * ASZ + buf * BSZ + row * 64];
            *(uint4*)&dstB[((c0)     ^ (row & 7)) * 8] = lo.v;
            *(uint4*)&dstB[((c0 + 1) ^ (row & 7)) * 8] = hi.v;
        } else {  // MODE 2
            if (k0 < C2) {
                int row = t >> 2;
                int kc  = (t & 3) * 16;
                const u16* bp = p2base + k0 + kc;
                const u16* r0p = bp + (size_t)vi0 * C2;
                const u16* r1p = bp + (size_t)vi1 * C2;
                const u16* r2p = bp + (size_t)vi2 * C2;
                union { uint4 v; u16 u[8]; } x0, x1, x2, y0, y1, y2, lo, hi;
                x0.v = *(const uint4*)r0p; y0.v = *(const uint4*)(r0p + 8);
                x1.v = *(const uint4*)r1p; y1.v = *(const uint4*)(r1p + 8);
                x2.v = *(const uint4*)r2p; y2.v = *(const uint4*)(r2p + 8);
#pragma unroll
                for (int e = 0; e < 8; ++e) {
                    lo.u[e] = f2bf(vw0 * bf2f(x0.u[e]) + vw1 * bf2f(x1.u[e]) + vw2 * bf2f(x2.u[e]));
                    hi.u[e] = f2bf(vw0 * bf2f(y0.u[e]) + vw1 * bf2f(y1.u[e]) + vw2 * bf2f(y2.u[e]));
                }
                int c0 = kc >> 3;
                u16* dstB = &smem[2 * ASZ + buf * BSZ + row * 64];
                *(uint4*)&dstB[((c0)     ^ (row & 7)) * 8] = lo.v;
                *(uint4*)&dstB[((c0 + 1) ^ (row & 7)) * 8] = hi.v;
            } else {
#pragma unroll
                for (int iss = 0; iss < COLT / 32; ++iss) {  // p1T DMA (K-contig)
                    int row = wv * (COLT / 4) + iss * 8;
                    const u16* g = p1T + (size_t)(cb0 + row + rl) * C1 + (k0 - C2) + cg;
                    __builtin_amdgcn_global_load_lds(
                        (const __attribute__((address_space(1))) unsigned int*)g,
                        (__attribute__((address_space(3))) unsigned int*)(&smem[2 * ASZ + buf * BSZ + row * 64]),
                        16, 0, 0);
                }
            }
        }
    };

    f32x4 acc[4][NI] = {};

    stage(0, 0);
    for (int kt = 0; kt < KT; ++kt) {
        __syncthreads();                                  // drains DMA + ds_writes
        if (kt + 1 < KT) stage((kt + 1) & 1, (kt + 1) * 64);
        const u16* As = &smem[(kt & 1) * ASZ];
        const u16* Bs = &smem[2 * ASZ + (kt & 1) * BSZ];
#pragma unroll
        for (int ks = 0; ks < 2; ++ks) {
            int csw = ((ks * 4 + q) ^ (lm & 7)) * 8;      // un-swizzle chunk offset
            short8 av[4], bv[NI];
#pragma unroll
            for (int mi = 0; mi < 4; ++mi)
                av[mi] = *(const short8*)&As[(wm0 + mi * 16 + lm) * 64 + csw];
#pragma unroll
            for (int ni = 0; ni < NI; ++ni)
                bv[ni] = *(const short8*)&Bs[(wn0 + ni * 16 + lm) * 64 + csw];
#pragma unroll
            for (int mi = 0; mi < 4; ++mi)
#pragma unroll
                for (int ni = 0; ni < NI; ++ni)
                    acc[mi][ni] = __builtin_amdgcn_mfma_f32_16x16x32_bf16(
                        av[mi], bv[ni], acc[mi][ni], 0, 0, 0);
        }
    }

    // ---- Epilogue (LDS overlay): Cs = COLT x 136 u16, reds = 256 floats ----
    u16*   Cs   = smem;                              // [colL*136 + m]
    float* reds = (float*)&smem[COLT * 136];         // [s*128 + chL]

    __syncthreads();                                  // all MFMA LDS reads done
    if (t < 256) reds[t] = 0.f;
    __syncthreads();

#pragma unroll
    for (int mi = 0; mi < 4; ++mi) {
        int chL = wm0 + mi * 16 + q * 4;             // local channel, 4 consecutive
        float bv4[4];
#pragma unroll
        for (int r = 0; r < 4; ++r) bv4[r] = bias[mb0 + chL + r];
        float s[4]  = {0.f, 0.f, 0.f, 0.f};
        float s2[4] = {0.f, 0.f, 0.f, 0.f};
#pragma unroll
        for (int ni = 0; ni < NI; ++ni) {
            int colL = wn0 + ni * 16 + lm;
            union { u16 u[4]; uint2 d; } pk;
#pragma unroll
            for (int r = 0; r < 4; ++r) {
                float v = acc[mi][ni][r] + bv4[r];
                s[r]  += v;
                s2[r] += v * v;
                pk.u[r] = f2bf(v);
            }
            *(uint2*)&Cs[colL * 136 + chL] = pk.d;
        }
#pragma unroll
        for (int r = 0; r < 4; ++r) {
            float a = s[r], b2 = s2[r];
#pragma unroll
            for (int off = 1; off < 16; off <<= 1) {
                a  += __shfl_xor(a, off, 64);
                b2 += __shfl_xor(b2, off, 64);
            }
            if (lm == 0) {
                atomicAdd(&reds[chL + r], a);          // LDS atomic (on-CU)
                atomicAdd(&reds[128 + chL + r], b2);
            }
        }
    }
    __syncthreads();

    // coalesced C-store: COLT rows x 128 m; each half-row = 64 u16 = 8 x uint4
    for (int u = t; u < COLT * 2; u += 256) {
        int c = u >> 1, h = u & 1;
        const u16* src = &Cs[c * 136 + h * 64];
        u16* dst = Ct + (size_t)(cb0 + c) * LDC + mb0 + h * 64;
#pragma unroll
        for (int jj = 0; jj < 8; ++jj)
            *(uint4*)(dst + jj * 8) = *(const uint4*)(src + jj * 8);
    }
    // accumulate block stats into the super-record (depth <= 16 per address)
    int recIdx = (MODE == 2) ? (blockIdx.y * REC0 + (blockIdx.x & (REC0 - 1)))
                             : (blockIdx.x & (REC1 - 1));
    atomicAdd(&partials[(size_t)recIdx * 256 + t], reds[t]);
}

// ---------------------------------------------------------------------------
// K8: final BN+ReLU on y1^T[col][c] (bf16) and transpose to out[b][c][n] (f32).
// Prologue folds part1's 32 super-records + g1/be1 into scale/shift in LDS.
__global__ __launch_bounds__(256) void finalize_kernel(const u16* __restrict__ y1T,
                                                       const float* __restrict__ part1,
                                                       const float* __restrict__ g1,
                                                       const float* __restrict__ be1,
                                                       float invN,
                                                       float* __restrict__ out) {
    __shared__ float tile[64][129];
    __shared__ float sc[O1], sh[O1];
    int t  = threadIdx.x;
    int b  = blockIdx.y;
    int n0 = blockIdx.x * 64;

    if (t < O1) {
        float s = 0.f, s2 = 0.f;
#pragma unroll 8
        for (int i = 0; i < REC1; ++i) {
            s  += part1[i * 256 + t];
            s2 += part1[i * 256 + 128 + t];
        }
        float mean = s * invN;
        float var  = fmaxf(s2 * invN - mean * mean, 0.f);
        float inv  = rsqrtf(var + BN_EPS);
        float scv  = g1[t] * inv;
        sc[t] = scv;
        sh[t] = be1[t] - mean * scv;
    }
    __syncthreads();

#pragma unroll
    for (int it = 0; it < 32; ++it) {
        int flat = it * 256 + t;
        int cl = flat >> 7;          // local col 0..63
        int c  = flat & 127;
        int col = b * NN + n0 + cl;
        float v = bf2f(y1T[(size_t)col * O1 + c]);
        tile[cl][c] = fmaxf(v * sc[c] + sh[c], 0.f);
    }
    __syncthreads();
#pragma unroll
    for (int it = 0; it < 32; ++it) {
        int flat = it * 256 + t;
        int c  = flat >> 6;          // channel 0..127
        int nl = flat & 63;
        out[(size_t)b * O1 * NN + (size_t)c * NN + n0 + nl] = tile[nl][c];
    }
}

// ---------------------------------------------------------------------------
extern "C" void kernel_launch(void* const* d_in, const int* in_sizes, int n_in,
                              void* d_out, int out_size, void* d_ws, size_t ws_size,
                              hipStream_t stream) {
    (void)in_sizes; (void)n_in; (void)out_size; (void)ws_size;

    const float* xyz1    = (const float*)d_in[0];
    const float* xyz2    = (const float*)d_in[1];
    const float* norm1   = (const float*)d_in[2];
    const float* norm2   = (const float*)d_in[3];
    const float* points1 = (const float*)d_in[4];
    const float* points2 = (const float*)d_in[5];
    const float* W0f     = (const float*)d_in[6];
    const float* b0      = (const float*)d_in[7];
    const float* g0      = (const float*)d_in[8];
    const float* be0     = (const float*)d_in[9];
    const float* W1f     = (const float*)d_in[10];
    const float* b1      = (const float*)d_in[11];
    const float* g1      = (const float*)d_in[12];
    const float* be1     = (const float*)d_in[13];
    float* out = (float*)d_out;

    // workspace carve-up (all 256B-aligned)
    char* w8 = (char*)d_ws;
    size_t off = 0;
    auto carve = [&](size_t bytes) { void* p = w8 + off; off += (bytes + 255) & ~(size_t)255; return p; };
    int*   idxW   = (int*)  carve((size_t)NCOL * 3 * sizeof(int));
    float* wW     = (float*)carve((size_t)NCOL * 3 * sizeof(float));
    u16*   p2T    = (u16*)  carve((size_t)BB * MM * C2 * 2);
    u16*   p1T    = (u16*)  carve((size_t)BB * NN * C1 * 2);
    u16*   W0b    = (u16*)  carve((size_t)O0 * CH0 * 2);
    u16*   W1b    = (u16*)  carve((size_t)O1 * O0 * 2);
    u16*   y0T    = (u16*)  carve((size_t)NCOL * O0 * 2);
    u16*   y1T    = (u16*)  carve((size_t)NCOL * O1 * 2);
    float* part0  = (float*)carve((size_t)2 * REC0 * 256 * sizeof(float)); // 128 KB
    float* part1  = (float*)carve((size_t)REC1 * 256 * sizeof(float));     // 32 KB

    const float invN = 1.0f / (float)NCOL;

    // 1024 3-NN blocks + 6656 prep blocks + 160 zero blocks
    fused_pre_kernel<<<7840, 256, 0, stream>>>(
        xyz1, xyz2, norm1, norm2, idxW, wW,
        points2, p2T, points1, p1T, W0f, W0b, W1f, W1b, part0, part1);

    // GEMM0 (MODE 2): interpolation fused into B staging; p1 channels via DMA
    gemm_bt_kernel<CH0, O0, 64, 2><<<dim3(NCOL / 64, O0 / 128), 256, 0, stream>>>(
        W0b, p2T, p1T, idxW, wW, y0T, b0, nullptr, nullptr, nullptr, invN, part0);

    // GEMM1 (MODE 1): fused BN0+ReLU on B; prologue folds part0+g0/be0
    gemm_bt_kernel<O0, O1, 64, 1><<<dim3(NCOL / 64, O1 / 128), 256, 0, stream>>>(
        W1b, y0T, nullptr, nullptr, nullptr, y1T, b1, part0, g0, be0, invN, part1);

    finalize_kernel<<<dim3(NN / 64, BB), 256, 0, stream>>>(y1T, part1, g1, be1, invN, out);
}